// Round 2
// baseline (206.115 us; speedup 1.0000x reference)
//
#include <hip/hip_runtime.h>
#include <cstddef>
#include <cstdint>

#define BB 8
#define TT 24
#define NN 1024
#define FF 3
#define HH 256
#define PP 12
#define RTOT (BB*TT*NN)   // 196608

// tab layout (floats):
// [0..8]      A spatial (3x3 row-major, pre-scaled by 1/16)
// [12..14]    g spatial (pre-scaled by 1/16)
// [16..87]    A_hd (8 heads x 3x3, pre-scaled by 1/sqrt(32))
// [96..119]   u_hd (8 heads x 3, pre-scaled by 1/sqrt(32))
// [128..6271] Vo (24 x 256)
// [6272..6527] co (256)
#define TAB_A   0
#define TAB_G   12
#define TAB_AHD 16
#define TAB_UHD 96
#define TAB_VO  128
#define TAB_CO  6272

// ---------- k_pre1: spatial score tables A (3x3), g (3) ----------
__global__ __launch_bounds__(256) void k_pre1(const float* __restrict__ w_s1,
                                              const float* __restrict__ w_s2,
                                              const float* __restrict__ w_in,
                                              const float* __restrict__ b_in,
                                              const float* __restrict__ b_s1,
                                              float* __restrict__ tab){
  __shared__ float P1[HH][3], P2[HH][3], wb1[HH], bs1[HH];
  const int c = threadIdx.x;
  float p10=0,p11=0,p12=0,p20=0,p21=0,p22=0,wb=0;
  for(int i=0;i<HH;++i){
    const float a = w_s1[c*HH+i], b = w_s2[c*HH+i];
    const float w0 = w_in[i*3], w1 = w_in[i*3+1], w2 = w_in[i*3+2];
    p10 = fmaf(a,w0,p10); p11 = fmaf(a,w1,p11); p12 = fmaf(a,w2,p12);
    p20 = fmaf(b,w0,p20); p21 = fmaf(b,w1,p21); p22 = fmaf(b,w2,p22);
    wb  = fmaf(a,b_in[i],wb);
  }
  P1[c][0]=p10; P1[c][1]=p11; P1[c][2]=p12;
  P2[c][0]=p20; P2[c][1]=p21; P2[c][2]=p22;
  wb1[c]=wb; bs1[c]=b_s1[c];
  __syncthreads();
  const float sc = 0.0625f;  // 1/sqrt(256)
  if(c < 9){
    const int f = c/3, g = c%3;
    float a = 0.f;
    for(int i=0;i<HH;++i) a = fmaf(P1[i][f], P2[i][g], a);
    tab[TAB_A + c] = a*sc;
  } else if(c >= 12 && c < 15){
    const int f = c-12;
    float a = 0.f;
    for(int i=0;i<HH;++i) a = fmaf(bs1[i]+wb1[i], P2[i][f], a);
    tab[TAB_G + f] = a*sc;
  }
}

// ---------- k_pre2: temporal tables A_hd, u_hd, and Vo, co ----------
__global__ __launch_bounds__(256) void k_pre2(const float* __restrict__ w_qkv,
                                              const float* __restrict__ b_qkv,
                                              const float* __restrict__ w_in,
                                              const float* __restrict__ b_in,
                                              const float* __restrict__ w_o,
                                              const float* __restrict__ b_o,
                                              float* __restrict__ tab){
  __shared__ float Qh[3][HH], Kh[3][HH], Vh[3][HH];
  __shared__ float cq[HH], ck_[HH], cv[HH];
  const int c = threadIdx.x;
  {
    float a0=0,a1=0,a2=0,cb=0;
    const float* wr = w_qkv + (size_t)c*HH;
    for(int j=0;j<HH;++j){
      const float w = wr[j];
      a0 = fmaf(w, w_in[j*3+0], a0);
      a1 = fmaf(w, w_in[j*3+1], a1);
      a2 = fmaf(w, w_in[j*3+2], a2);
      cb = fmaf(w, b_in[j], cb);
    }
    Qh[0][c]=a0; Qh[1][c]=a1; Qh[2][c]=a2; cq[c]=cb + b_qkv[c];
  }
  {
    float a0=0,a1=0,a2=0,cb=0;
    const float* wr = w_qkv + (size_t)(HH+c)*HH;
    for(int j=0;j<HH;++j){
      const float w = wr[j];
      a0 = fmaf(w, w_in[j*3+0], a0);
      a1 = fmaf(w, w_in[j*3+1], a1);
      a2 = fmaf(w, w_in[j*3+2], a2);
      cb = fmaf(w, b_in[j], cb);
    }
    Kh[0][c]=a0; Kh[1][c]=a1; Kh[2][c]=a2; ck_[c]=cb + b_qkv[HH+c];
  }
  {
    float a0=0,a1=0,a2=0,cb=0;
    const float* wr = w_qkv + (size_t)(2*HH+c)*HH;
    for(int j=0;j<HH;++j){
      const float w = wr[j];
      a0 = fmaf(w, w_in[j*3+0], a0);
      a1 = fmaf(w, w_in[j*3+1], a1);
      a2 = fmaf(w, w_in[j*3+2], a2);
      cb = fmaf(w, b_in[j], cb);
    }
    Vh[0][c]=a0; Vh[1][c]=a1; Vh[2][c]=a2; cv[c]=cb + b_qkv[2*HH+c];
  }
  __syncthreads();
  const float ts = 0.17677669529663687f;  // 1/sqrt(32)
  if(c < 72){
    const int hd = c/9, r = c%9, f = r/3, g = r%3;
    float a=0.f;
    for(int i=0;i<32;++i) a = fmaf(Qh[f][hd*32+i], Kh[g][hd*32+i], a);
    tab[TAB_AHD + c] = a*ts;
  }
  if(c >= 96 && c < 120){
    const int i2 = c-96, hd = i2/3, g = i2%3;
    float a=0.f;
    for(int i=0;i<32;++i) a = fmaf(cq[hd*32+i], Kh[g][hd*32+i], a);
    tab[TAB_UHD + i2] = a*ts;
  }
  {
    float vo[24];
    #pragma unroll
    for(int j=0;j<24;++j) vo[j]=0.f;
    float coacc = 0.f;
    const float* wor = w_o + (size_t)c*HH;
    #pragma unroll
    for(int hd=0; hd<8; ++hd){
      for(int i=0;i<32;++i){
        const float w = wor[hd*32+i];
        vo[hd*3+0] = fmaf(Vh[0][hd*32+i], w, vo[hd*3+0]);
        vo[hd*3+1] = fmaf(Vh[1][hd*32+i], w, vo[hd*3+1]);
        vo[hd*3+2] = fmaf(Vh[2][hd*32+i], w, vo[hd*3+2]);
        coacc = fmaf(cv[hd*32+i], w, coacc);
      }
    }
    #pragma unroll
    for(int j=0;j<24;++j) tab[TAB_VO + j*HH + c] = vo[j];
    tab[TAB_CO + c] = coacc + b_o[c];
  }
}

// ---------- k_spatial: y[bt,q,:] = softmax_m(x_q.A.x_m + g.x_m) @ x_bt ----------
__global__ __launch_bounds__(256) void k_spatial(const float* __restrict__ x,
                                                 const float* __restrict__ tab,
                                                 float* __restrict__ y){
  const int bt = blockIdx.x >> 2;
  const int qt = blockIdx.x & 3;
  const float* xb = x + (size_t)bt*NN*3;
  __shared__ __align__(16) float xs[NN*3];
  __shared__ __align__(16) float ds[NN*3];
  __shared__ float es[NN];
  const int tid = threadIdx.x;
  #pragma unroll
  for(int v=0;v<3;++v)
    *(float4*)&xs[tid*12 + v*4] = *(const float4*)&xb[tid*12 + v*4];
  float A[9], g3[3];
  #pragma unroll
  for(int i=0;i<9;++i) A[i] = tab[TAB_A+i];
  #pragma unroll
  for(int i=0;i<3;++i) g3[i] = tab[TAB_G+i];
  __syncthreads();
  #pragma unroll
  for(int r=0;r<4;++r){
    const int m = tid*4 + r;
    const float x0 = xs[m*3], x1 = xs[m*3+1], x2 = xs[m*3+2];
    ds[m*3+0] = fmaf(A[0],x0, fmaf(A[1],x1, A[2]*x2));
    ds[m*3+1] = fmaf(A[3],x0, fmaf(A[4],x1, A[5]*x2));
    ds[m*3+2] = fmaf(A[6],x0, fmaf(A[7],x1, A[8]*x2));
    es[m]     = fmaf(g3[0],x0, fmaf(g3[1],x1, g3[2]*x2));
  }
  __syncthreads();
  const int q = qt*256 + tid;
  const float xq0 = xs[q*3], xq1 = xs[q*3+1], xq2 = xs[q*3+2];
  float psum=0.f, y0=0.f, y1=0.f, y2=0.f;
  #pragma unroll 4
  for(int m=0;m<NN;++m){
    const float s = fmaf(xq0, ds[m*3], fmaf(xq1, ds[m*3+1], fmaf(xq2, ds[m*3+2], es[m])));
    const float p = __expf(s);
    psum += p;
    y0 = fmaf(p, xs[m*3+0], y0);
    y1 = fmaf(p, xs[m*3+1], y1);
    y2 = fmaf(p, xs[m*3+2], y2);
  }
  const float rinv = 1.f/psum;
  y[((size_t)bt*NN + q)*3 + 0] = y0*rinv;
  y[((size_t)bt*NN + q)*3 + 1] = y1*rinv;
  y[((size_t)bt*NN + q)*3 + 2] = y2*rinv;
}

// ---------- k_temporal: per (b,n) 8-head attention over t in 3-dim space ----------
__global__ __launch_bounds__(256) void k_temporal(const float* __restrict__ y,
                                                  const float* __restrict__ tab,
                                                  float* __restrict__ Yout){
  __shared__ float sA[104];   // [0..71] A_hd, [80..103] u_hd
  const int tid = threadIdx.x;
  if(tid < 104) sA[tid] = tab[TAB_AHD + tid];
  __syncthreads();
  const int bn = blockIdx.x*256 + tid;
  const int b = bn >> 10, n = bn & (NN-1);
  float yt[TT][3];
  #pragma unroll
  for(int t=0;t<TT;++t){
    const size_t base = (((size_t)b*TT + t)*NN + n)*3;
    yt[t][0] = y[base]; yt[t][1] = y[base+1]; yt[t][2] = y[base+2];
  }
  const float yq0 = yt[TT-1][0], yq1 = yt[TT-1][1], yq2 = yt[TT-1][2];
  float out[24];
  #pragma unroll
  for(int hd=0; hd<8; ++hd){
    const float z0 = fmaf(yq0,sA[hd*9+0],fmaf(yq1,sA[hd*9+3],fmaf(yq2,sA[hd*9+6], sA[80+hd*3+0])));
    const float z1 = fmaf(yq0,sA[hd*9+1],fmaf(yq1,sA[hd*9+4],fmaf(yq2,sA[hd*9+7], sA[80+hd*3+1])));
    const float z2 = fmaf(yq0,sA[hd*9+2],fmaf(yq1,sA[hd*9+5],fmaf(yq2,sA[hd*9+8], sA[80+hd*3+2])));
    float p[TT]; float sum=0.f;
    #pragma unroll
    for(int t=0;t<TT;++t){
      p[t] = __expf(fmaf(z0,yt[t][0],fmaf(z1,yt[t][1],z2*yt[t][2])));
      sum += p[t];
    }
    const float rinv = 1.f/sum;
    float Y0=0.f,Y1=0.f,Y2=0.f;
    #pragma unroll
    for(int t=0;t<TT;++t){
      Y0 = fmaf(p[t],yt[t][0],Y0);
      Y1 = fmaf(p[t],yt[t][1],Y1);
      Y2 = fmaf(p[t],yt[t][2],Y2);
    }
    out[hd*3+0]=Y0*rinv; out[hd*3+1]=Y1*rinv; out[hd*3+2]=Y2*rinv;
  }
  #pragma unroll
  for(int j=0;j<24;++j) Yout[(size_t)bn*24 + j] = out[j];
}

// ---------- k_oo: oo = Y @ Vo + co   (8192 x 24) @ (24 x 256) ----------
__global__ __launch_bounds__(256) void k_oo(const float* __restrict__ Yin,
                                            const float* __restrict__ tab,
                                            float* __restrict__ oo){
  __shared__ float Ys[64*24];
  const int rowb = blockIdx.x*64;
  const int tid = threadIdx.x;
  #pragma unroll
  for(int i=0;i<6;++i) Ys[tid*6+i] = Yin[(size_t)rowb*24 + tid*6+i];
  const int c = tid;
  float vo[24];
  #pragma unroll
  for(int j=0;j<24;++j) vo[j] = tab[TAB_VO + j*HH + c];
  const float cc = tab[TAB_CO + c];
  __syncthreads();
  for(int r=0;r<64;++r){
    float acc = cc;
    #pragma unroll
    for(int j=0;j<24;++j) acc = fmaf(Ys[r*24+j], vo[j], acc);
    oo[(size_t)(rowb+r)*HH + c] = acc;
  }
}

// ---------- generic GEMM: C = op(A @ W^T + bias), K=256 fixed ----------
#define MAD_ROW(i, AV) \
  acc[i][0]=fmaf(AV.x,b0.x,acc[i][0]); acc[i][1]=fmaf(AV.x,b0.y,acc[i][1]); acc[i][2]=fmaf(AV.x,b0.z,acc[i][2]); acc[i][3]=fmaf(AV.x,b0.w,acc[i][3]); \
  acc[i][0]=fmaf(AV.y,b1.x,acc[i][0]); acc[i][1]=fmaf(AV.y,b1.y,acc[i][1]); acc[i][2]=fmaf(AV.y,b1.z,acc[i][2]); acc[i][3]=fmaf(AV.y,b1.w,acc[i][3]); \
  acc[i][0]=fmaf(AV.z,b2.x,acc[i][0]); acc[i][1]=fmaf(AV.z,b2.y,acc[i][1]); acc[i][2]=fmaf(AV.z,b2.z,acc[i][2]); acc[i][3]=fmaf(AV.z,b2.w,acc[i][3]); \
  acc[i][0]=fmaf(AV.w,b3.x,acc[i][0]); acc[i][1]=fmaf(AV.w,b3.y,acc[i][1]); acc[i][2]=fmaf(AV.w,b3.z,acc[i][2]); acc[i][3]=fmaf(AV.w,b3.w,acc[i][3]);

template<bool RELU, bool BIAS, bool SCATTER>
__global__ __launch_bounds__(256) void k_gemm(const float* __restrict__ A,
                                              const float* __restrict__ W,
                                              const float* __restrict__ bias,
                                              float* __restrict__ C,
                                              int Ncols){
  __shared__ __align__(16) float As[64][20];
  __shared__ __align__(16) float Bs[16][68];
  const int rowb = blockIdx.y * 64;
  const int colb = blockIdx.x * 64;
  const int tid = threadIdx.x;
  const int tx = tid & 15;
  const int ty = tid >> 4;
  const int sr = tid >> 2;         // 0..63
  const int sc = (tid & 3) * 4;    // 0,4,8,12
  float acc[4][4] = {};
  for(int kt = 0; kt < 16; ++kt){
    const float4 av = *(const float4*)&A[(size_t)(rowb+sr)*HH + kt*16 + sc];
    float4 wv = make_float4(0.f,0.f,0.f,0.f);
    if(colb + sr < Ncols) wv = *(const float4*)&W[(size_t)(colb+sr)*HH + kt*16 + sc];
    __syncthreads();
    *(float4*)&As[sr][sc] = av;
    Bs[sc+0][sr] = wv.x; Bs[sc+1][sr] = wv.y; Bs[sc+2][sr] = wv.z; Bs[sc+3][sr] = wv.w;
    __syncthreads();
    #pragma unroll
    for(int kc = 0; kc < 4; ++kc){
      const float4 a0 = *(const float4*)&As[ty*4+0][kc*4];
      const float4 a1 = *(const float4*)&As[ty*4+1][kc*4];
      const float4 a2 = *(const float4*)&As[ty*4+2][kc*4];
      const float4 a3 = *(const float4*)&As[ty*4+3][kc*4];
      const float4 b0 = *(const float4*)&Bs[kc*4+0][tx*4];
      const float4 b1 = *(const float4*)&Bs[kc*4+1][tx*4];
      const float4 b2 = *(const float4*)&Bs[kc*4+2][tx*4];
      const float4 b3 = *(const float4*)&Bs[kc*4+3][tx*4];
      MAD_ROW(0, a0) MAD_ROW(1, a1) MAD_ROW(2, a2) MAD_ROW(3, a3)
    }
  }
  #pragma unroll
  for(int i = 0; i < 4; ++i){
    const int row = rowb + ty*4 + i;
    if(!SCATTER){
      float4 v;
      v.x = acc[i][0]; v.y = acc[i][1]; v.z = acc[i][2]; v.w = acc[i][3];
      const int col = colb + tx*4;
      if(BIAS){ v.x += bias[col]; v.y += bias[col+1]; v.z += bias[col+2]; v.w += bias[col+3]; }
      if(RELU){ v.x = v.x>0.f?v.x:0.f; v.y = v.y>0.f?v.y:0.f; v.z = v.z>0.f?v.z:0.f; v.w = v.w>0.f?v.w:0.f; }
      *(float4*)&C[(size_t)row*HH + col] = v;
    } else {
      #pragma unroll
      for(int j = 0; j < 4; ++j){
        const int col = colb + tx*4 + j;
        if(col < Ncols){
          float v = acc[i][j];
          if(BIAS) v += bias[col];
          if(RELU) v = v>0.f?v:0.f;
          const int b = row >> 10, n = row & 1023;
          const int p = col / 3, f = col - p*3;
          C[(size_t)(((b*PP + p)*NN + n)*FF + f)] = v;
        }
      }
    }
  }
}

extern "C" void kernel_launch(void* const* d_in, const int* in_sizes, int n_in,
                              void* d_out, int out_size, void* d_ws, size_t ws_size,
                              hipStream_t stream){
  (void)in_sizes; (void)n_in; (void)out_size; (void)ws_size;
  const float* x     = (const float*)d_in[0];
  const float* w_in  = (const float*)d_in[2];
  const float* b_in  = (const float*)d_in[3];
  const float* w_s1  = (const float*)d_in[4];
  const float* b_s1  = (const float*)d_in[5];
  const float* w_s2  = (const float*)d_in[6];
  const float* w_qkv = (const float*)d_in[8];
  const float* b_qkv = (const float*)d_in[9];
  const float* w_o   = (const float*)d_in[10];
  const float* b_o   = (const float*)d_in[11];
  const float* w_g1  = (const float*)d_in[12];
  const float* b_g1  = (const float*)d_in[13];
  const float* w_g2  = (const float*)d_in[14];
  const float* b_g2  = (const float*)d_in[15];
  const float* w_out = (const float*)d_in[16];
  const float* b_out = (const float*)d_in[17];
  float* ws = (float*)d_ws;

  float* tab = ws;                 // 8192 floats
  float* y   = ws + 8192;          // 589824
  float* Y   = ws + 598016;        // 196608
  float* oo  = ws + 794624;        // 2097152
  float* g1  = ws + 2891776;       // 2097152
  float* g2  = ws + 4988928;       // 2097152 (end 7086080 floats = 28.3 MB)
  float* outp = (float*)d_out;

  k_pre1<<<1, 256, 0, stream>>>(w_s1, w_s2, w_in, b_in, b_s1, tab);
  k_pre2<<<1, 256, 0, stream>>>(w_qkv, b_qkv, w_in, b_in, w_o, b_o, tab);
  k_spatial<<<BB*TT*4, 256, 0, stream>>>(x, tab, y);
  k_temporal<<<BB*NN/256, 256, 0, stream>>>(y, tab, Y);
  k_oo<<<BB*NN/64, 256, 0, stream>>>(Y, tab, oo);
  k_gemm<true, true,false><<<dim3(4, BB*NN/64), 256, 0, stream>>>(oo, w_g1, b_g1, g1, HH);
  k_gemm<true, true,false><<<dim3(4, BB*NN/64), 256, 0, stream>>>(g1, w_g2, b_g2, g2, HH);
  k_gemm<false,true,true ><<<dim3(1, BB*NN/64), 256, 0, stream>>>(g2, w_out, b_out, outp, PP*FF);
}

// Round 3
// 181.127 us; speedup vs baseline: 1.1380x; 1.1380x over previous
//
#include <hip/hip_runtime.h>
#include <cstddef>
#include <cstdint>
#include <cmath>

#define BB 8
#define TT 24
#define NN 1024
#define FF 3
#define HH 256
#define PP 12
#define RTOT (BB*TT*NN)   // 196608
#define LOG2E 1.4426950408889634f

// ---- ws float offsets ----
#define TAB_A    0      // 9: spatial A (x log2e/16)
#define TAB_G    12     // 3: spatial g (x log2e/16)
#define TAB_AHD  16     // 72: temporal A_hd (x log2e/sqrt32)
#define TAB_UHD  96     // 24: temporal u_hd (x log2e/sqrt32)
#define TAB_VO2  128    // 24x256: Vo @ w_g1^T
#define TAB_C2   6272   // 256
#define P1OFF    8192   // 3x256
#define P2OFF    8960   // 3x256
#define WBOFF    9728   // 256
#define QHOFF    9984   // 3x256
#define KHOFF    10752  // 3x256
#define VHOFF    11520  // 3x256
#define CQOFF    12288  // 256
#define CVOFF    12544  // 256
#define VO1OFF   12800  // 24x256
#define CO1OFF   18944  // 256
#define PHIOFF   19456  // 196608 * 8 floats
#define YSPOFF   1592320  // 196608*3
#define YTOFF    2182144  // 8192*24
#define G1OFF    2378752  // 8192*256
#define G2OFF    4475904  // 8192*256  (end 6573056 floats = 26.3 MB)

// ---------- k_preS: P1/P2 = rows of {w_s1,w_s2} projected onto w_in cols; WB = w_s1 @ b_in
// grid 8 x 256. thread-quad per row.
__global__ __launch_bounds__(256) void k_preS(const float* __restrict__ w_s1,
                                              const float* __restrict__ w_s2,
                                              const float* __restrict__ w_in,
                                              const float* __restrict__ b_in,
                                              float* __restrict__ ws){
  __shared__ float swin[768], sbin[256];
  const int tid = threadIdx.x;
  swin[tid] = w_in[tid]; swin[256+tid] = w_in[256+tid]; swin[512+tid] = w_in[512+tid];
  sbin[tid] = b_in[tid];
  __syncthreads();
  const int r = blockIdx.x*64 + (tid>>2);
  const int p = tid & 3;
  const float* row = (r < 256) ? (w_s1 + (size_t)r*HH) : (w_s2 + (size_t)(r-256)*HH);
  float p0=0.f,p1=0.f,p2=0.f,wb=0.f;
  #pragma unroll 4
  for(int c4=0;c4<16;++c4){
    const int i0 = p*64 + c4*4;
    const float4 v = *(const float4*)&row[i0];
    p0=fmaf(v.x,swin[i0*3+0],p0); p1=fmaf(v.x,swin[i0*3+1],p1); p2=fmaf(v.x,swin[i0*3+2],p2); wb=fmaf(v.x,sbin[i0],wb);
    p0=fmaf(v.y,swin[i0*3+3],p0); p1=fmaf(v.y,swin[i0*3+4],p1); p2=fmaf(v.y,swin[i0*3+5],p2); wb=fmaf(v.y,sbin[i0+1],wb);
    p0=fmaf(v.z,swin[i0*3+6],p0); p1=fmaf(v.z,swin[i0*3+7],p1); p2=fmaf(v.z,swin[i0*3+8],p2); wb=fmaf(v.z,sbin[i0+2],wb);
    p0=fmaf(v.w,swin[i0*3+9],p0); p1=fmaf(v.w,swin[i0*3+10],p1);p2=fmaf(v.w,swin[i0*3+11],p2);wb=fmaf(v.w,sbin[i0+3],wb);
  }
  p0 += __shfl_xor(p0,1); p0 += __shfl_xor(p0,2);
  p1 += __shfl_xor(p1,1); p1 += __shfl_xor(p1,2);
  p2 += __shfl_xor(p2,1); p2 += __shfl_xor(p2,2);
  wb += __shfl_xor(wb,1); wb += __shfl_xor(wb,2);
  if(p==0){
    if(r < 256){
      ws[P1OFF + 0*256 + r] = p0; ws[P1OFF + 1*256 + r] = p1; ws[P1OFF + 2*256 + r] = p2;
      ws[WBOFF + r] = wb;
    } else {
      const int c = r-256;
      ws[P2OFF + 0*256 + c] = p0; ws[P2OFF + 1*256 + c] = p1; ws[P2OFF + 2*256 + c] = p2;
    }
  }
}

// ---------- k_preQKV: QH/KH/VH = rows of w_qkv projected on w_in; CQ/CV consts
// grid 12 x 256
__global__ __launch_bounds__(256) void k_preQKV(const float* __restrict__ w_qkv,
                                                const float* __restrict__ b_qkv,
                                                const float* __restrict__ w_in,
                                                const float* __restrict__ b_in,
                                                float* __restrict__ ws){
  __shared__ float swin[768], sbin[256];
  const int tid = threadIdx.x;
  swin[tid] = w_in[tid]; swin[256+tid] = w_in[256+tid]; swin[512+tid] = w_in[512+tid];
  sbin[tid] = b_in[tid];
  __syncthreads();
  const int r = blockIdx.x*64 + (tid>>2);
  const int p = tid & 3;
  const float* row = w_qkv + (size_t)r*HH;
  float p0=0.f,p1=0.f,p2=0.f,wb=0.f;
  #pragma unroll 4
  for(int c4=0;c4<16;++c4){
    const int i0 = p*64 + c4*4;
    const float4 v = *(const float4*)&row[i0];
    p0=fmaf(v.x,swin[i0*3+0],p0); p1=fmaf(v.x,swin[i0*3+1],p1); p2=fmaf(v.x,swin[i0*3+2],p2); wb=fmaf(v.x,sbin[i0],wb);
    p0=fmaf(v.y,swin[i0*3+3],p0); p1=fmaf(v.y,swin[i0*3+4],p1); p2=fmaf(v.y,swin[i0*3+5],p2); wb=fmaf(v.y,sbin[i0+1],wb);
    p0=fmaf(v.z,swin[i0*3+6],p0); p1=fmaf(v.z,swin[i0*3+7],p1); p2=fmaf(v.z,swin[i0*3+8],p2); wb=fmaf(v.z,sbin[i0+2],wb);
    p0=fmaf(v.w,swin[i0*3+9],p0); p1=fmaf(v.w,swin[i0*3+10],p1);p2=fmaf(v.w,swin[i0*3+11],p2);wb=fmaf(v.w,sbin[i0+3],wb);
  }
  p0 += __shfl_xor(p0,1); p0 += __shfl_xor(p0,2);
  p1 += __shfl_xor(p1,1); p1 += __shfl_xor(p1,2);
  p2 += __shfl_xor(p2,1); p2 += __shfl_xor(p2,2);
  wb += __shfl_xor(wb,1); wb += __shfl_xor(wb,2);
  if(p==0){
    if(r < 256){
      ws[QHOFF + 0*256 + r] = p0; ws[QHOFF + 1*256 + r] = p1; ws[QHOFF + 2*256 + r] = p2;
      ws[CQOFF + r] = wb + b_qkv[r];
    } else if(r < 512){
      const int c = r-256;
      ws[KHOFF + 0*256 + c] = p0; ws[KHOFF + 1*256 + c] = p1; ws[KHOFF + 2*256 + c] = p2;
    } else {
      const int c = r-512;
      ws[VHOFF + 0*256 + c] = p0; ws[VHOFF + 1*256 + c] = p1; ws[VHOFF + 2*256 + c] = p2;
      ws[CVOFF + c] = wb + b_qkv[r];
    }
  }
}

// ---------- k_tab: A,g (spatial) and A_hd,u_hd (temporal), all pre-scaled with log2e
__global__ __launch_bounds__(256) void k_tab(const float* __restrict__ b_s1,
                                             float* __restrict__ ws){
  __shared__ float sP1[768], sP2[768], sQ[768], sK[768], sBW[256], sCQ[256];
  const int tid = threadIdx.x;
  sP1[tid]=ws[P1OFF+tid]; sP1[256+tid]=ws[P1OFF+256+tid]; sP1[512+tid]=ws[P1OFF+512+tid];
  sP2[tid]=ws[P2OFF+tid]; sP2[256+tid]=ws[P2OFF+256+tid]; sP2[512+tid]=ws[P2OFF+512+tid];
  sQ[tid]=ws[QHOFF+tid];  sQ[256+tid]=ws[QHOFF+256+tid];  sQ[512+tid]=ws[QHOFF+512+tid];
  sK[tid]=ws[KHOFF+tid];  sK[256+tid]=ws[KHOFF+256+tid];  sK[512+tid]=ws[KHOFF+512+tid];
  sBW[tid]=b_s1[tid]+ws[WBOFF+tid];
  sCQ[tid]=ws[CQOFF+tid];
  __syncthreads();
  const float SC = 0.0625f * LOG2E;
  const float TS = 0.17677669529663687f * LOG2E;
  if(tid < 9){
    const int f = tid/3, g = tid%3;
    float a=0.f;
    for(int c=0;c<256;++c) a = fmaf(sP1[f*256+c], sP2[g*256+c], a);
    ws[TAB_A+tid] = a*SC;
  } else if(tid >= 12 && tid < 15){
    const int f = tid-12;
    float a=0.f;
    for(int c=0;c<256;++c) a = fmaf(sBW[c], sP2[f*256+c], a);
    ws[TAB_G+f] = a*SC;
  } else if(tid >= 32 && tid < 104){
    const int i2 = tid-32;
    const int hd = i2/9, rr = i2%9, f = rr/3, g = rr%3;
    float a=0.f;
    for(int i=0;i<32;++i) a = fmaf(sQ[f*256+hd*32+i], sK[g*256+hd*32+i], a);
    ws[TAB_AHD+i2] = a*TS;
  } else if(tid >= 128 && tid < 152){
    const int i2 = tid-128;
    const int hd = i2/3, g = i2%3;
    float a=0.f;
    for(int i=0;i<32;++i) a = fmaf(sCQ[hd*32+i], sK[g*256+hd*32+i], a);
    ws[TAB_UHD+i2] = a*TS;
  }
}

// ---------- k_vo1: VO1[24][256] = per-head V-projections through w_o; CO1 const
// grid 4 x 256: c = blk*64 + tid/4, p = tid%4 (p covers i in [p*64,p*64+64) = heads 2p,2p+1)
__global__ __launch_bounds__(256) void k_vo1(const float* __restrict__ w_o,
                                             const float* __restrict__ b_o,
                                             float* __restrict__ ws){
  __shared__ float sVH[768], sCV[256];
  const int tid = threadIdx.x;
  sVH[tid]=ws[VHOFF+tid]; sVH[256+tid]=ws[VHOFF+256+tid]; sVH[512+tid]=ws[VHOFF+512+tid];
  sCV[tid]=ws[CVOFF+tid];
  __syncthreads();
  const int c = blockIdx.x*64 + (tid>>2);
  const int p = tid & 3;
  float v[6] = {0,0,0,0,0,0};
  float cop = 0.f;
  #pragma unroll 4
  for(int c4=0;c4<16;++c4){
    const int i0 = p*64 + c4*4;
    const float4 w = *(const float4*)&w_o[(size_t)c*HH + i0];
    #pragma unroll
    for(int e=0;e<4;++e){
      const int i = i0+e;
      const float we = (e==0)?w.x:(e==1)?w.y:(e==2)?w.z:w.w;
      const int hl = (i>>5)&1;
      v[hl*3+0] = fmaf(sVH[0*256+i], we, v[hl*3+0]);
      v[hl*3+1] = fmaf(sVH[1*256+i], we, v[hl*3+1]);
      v[hl*3+2] = fmaf(sVH[2*256+i], we, v[hl*3+2]);
      cop = fmaf(sCV[i], we, cop);
    }
  }
  cop += __shfl_xor(cop,1); cop += __shfl_xor(cop,2);
  #pragma unroll
  for(int hl=0; hl<2; ++hl)
    #pragma unroll
    for(int f=0; f<3; ++f)
      ws[VO1OFF + ((2*p+hl)*3+f)*256 + c] = v[hl*3+f];
  if(p==0) ws[CO1OFF + c] = cop + b_o[c];
}

// ---------- k_vo2: VO2 = VO1 @ w_g1^T ; C2 = CO1 @ w_g1^T + b_g1
// grid 100 x 256: jj = blk/4 (0..24; 24 => CO1 row), c = (blk%4)*64 + tid/4, p = tid%4
__global__ __launch_bounds__(256) void k_vo2(const float* __restrict__ w_g1,
                                             const float* __restrict__ b_g1,
                                             float* __restrict__ ws){
  __shared__ float srow[256];
  const int tid = threadIdx.x;
  const int jj = blockIdx.x >> 2;
  srow[tid] = (jj < 24) ? ws[VO1OFF + jj*256 + tid] : ws[CO1OFF + tid];
  __syncthreads();
  const int c = (blockIdx.x & 3)*64 + (tid>>2);
  const int p = tid & 3;
  float a = 0.f;
  #pragma unroll 4
  for(int c4=0;c4<16;++c4){
    const int i0 = p*64 + c4*4;
    const float4 w = *(const float4*)&w_g1[(size_t)c*HH + i0];
    a = fmaf(w.x, srow[i0+0], a);
    a = fmaf(w.y, srow[i0+1], a);
    a = fmaf(w.z, srow[i0+2], a);
    a = fmaf(w.w, srow[i0+3], a);
  }
  a += __shfl_xor(a,1); a += __shfl_xor(a,2);
  if(p==0){
    if(jj < 24) ws[TAB_VO2 + jj*256 + c] = a;
    else        ws[TAB_C2 + c] = a + b_g1[c];
  }
}

// ---------- k_phi: phi8[m] = {A.x_m (3), g.x_m, x_m (3), 0}  (A,g pre-scaled)
__global__ __launch_bounds__(256) void k_phi(const float* __restrict__ x,
                                             const float* __restrict__ ws,
                                             float4* __restrict__ phi){
  const int idx = blockIdx.x*256 + threadIdx.x;
  const float x0 = x[idx*3], x1 = x[idx*3+1], x2 = x[idx*3+2];
  const float* A = ws + TAB_A;
  const float* g = ws + TAB_G;
  float4 pa, pb;
  pa.x = fmaf(A[0],x0, fmaf(A[1],x1, A[2]*x2));
  pa.y = fmaf(A[3],x0, fmaf(A[4],x1, A[5]*x2));
  pa.z = fmaf(A[6],x0, fmaf(A[7],x1, A[8]*x2));
  pa.w = fmaf(g[0],x0, fmaf(g[1],x1, g[2]*x2));
  pb.x = x0; pb.y = x1; pb.z = x2; pb.w = 0.f;
  phi[idx*2]   = pa;
  phi[idx*2+1] = pb;
}

// ---------- k_spatial: y[bt,q,:] = softmax_m(xq.A.xm + g.xm) @ x  — LDS-free
// grid 768 (bt*4+qt) x 256
__global__ __launch_bounds__(256) void k_spatial(const float* __restrict__ x,
                                                 const float4* __restrict__ phi,
                                                 float* __restrict__ y){
  const int bt = blockIdx.x >> 2;
  const int q  = (blockIdx.x & 3)*256 + threadIdx.x;
  const int gq = bt*NN + q;
  const float xq0 = x[gq*3], xq1 = x[gq*3+1], xq2 = x[gq*3+2];
  const float4* ph = phi + (size_t)bt*NN*2;
  float psum = 0.f, y0 = 0.f, y1 = 0.f, y2 = 0.f;
  #pragma unroll 8
  for(int m = 0; m < NN; ++m){
    const float4 a = ph[2*m];
    const float4 b = ph[2*m+1];
    const float s = fmaf(xq0, a.x, fmaf(xq1, a.y, fmaf(xq2, a.z, a.w)));
    const float p = exp2f(s);
    psum += p;
    y0 = fmaf(p, b.x, y0);
    y1 = fmaf(p, b.y, y1);
    y2 = fmaf(p, b.z, y2);
  }
  const float rinv = 1.f/psum;
  y[(size_t)gq*3+0] = y0*rinv;
  y[(size_t)gq*3+1] = y1*rinv;
  y[(size_t)gq*3+2] = y2*rinv;
}

// ---------- k_temporal: one thread per (b,n,head); query = t=T-1
// grid 256 x 256
__global__ __launch_bounds__(256) void k_temporal(const float* __restrict__ y,
                                                  const float* __restrict__ ws,
                                                  float* __restrict__ Yt){
  __shared__ float sA[96];
  const int tid = threadIdx.x;
  if(tid < 72) sA[tid] = ws[TAB_AHD + tid];
  else if(tid < 96) sA[tid] = ws[TAB_UHD + tid - 72];
  __syncthreads();
  const int g = blockIdx.x*256 + tid;
  const int bn = g >> 3, hd = g & 7;
  const int b = bn >> 10, n = bn & (NN-1);
  float yt[TT][3];
  #pragma unroll
  for(int t=0;t<TT;++t){
    const size_t base = (((size_t)b*TT + t)*NN + n)*3;
    yt[t][0]=y[base]; yt[t][1]=y[base+1]; yt[t][2]=y[base+2];
  }
  const float yq0 = yt[TT-1][0], yq1 = yt[TT-1][1], yq2 = yt[TT-1][2];
  const float z0 = fmaf(yq0,sA[hd*9+0],fmaf(yq1,sA[hd*9+3],fmaf(yq2,sA[hd*9+6], sA[72+hd*3+0])));
  const float z1 = fmaf(yq0,sA[hd*9+1],fmaf(yq1,sA[hd*9+4],fmaf(yq2,sA[hd*9+7], sA[72+hd*3+1])));
  const float z2 = fmaf(yq0,sA[hd*9+2],fmaf(yq1,sA[hd*9+5],fmaf(yq2,sA[hd*9+8], sA[72+hd*3+2])));
  float psum=0.f, Y0=0.f, Y1=0.f, Y2=0.f;
  #pragma unroll
  for(int t=0;t<TT;++t){
    const float p = exp2f(fmaf(z0,yt[t][0],fmaf(z1,yt[t][1],z2*yt[t][2])));
    psum += p;
    Y0 = fmaf(p,yt[t][0],Y0); Y1 = fmaf(p,yt[t][1],Y1); Y2 = fmaf(p,yt[t][2],Y2);
  }
  const float rinv = 1.f/psum;
  Yt[(size_t)bn*24 + hd*3 + 0] = Y0*rinv;
  Yt[(size_t)bn*24 + hd*3 + 1] = Y1*rinv;
  Yt[(size_t)bn*24 + hd*3 + 2] = Y2*rinv;
}

// ---------- k_g1: g1 = relu(Yt @ VO2 + C2)   (8192x24)@(24x256)
// grid 256 x 256, 32 rows/block
__global__ __launch_bounds__(256) void k_g1(const float* __restrict__ ws,
                                            float* __restrict__ g1){
  __shared__ float sY[768];
  const int tid = threadIdx.x;
  const int rowb = blockIdx.x*32;
  const float* Yt = ws + YTOFF;
  sY[tid] = Yt[(size_t)rowb*24 + tid];
  sY[256+tid] = Yt[(size_t)rowb*24 + 256 + tid];
  sY[512+tid] = Yt[(size_t)rowb*24 + 512 + tid];
  float vj[24];
  #pragma unroll
  for(int j=0;j<24;++j) vj[j] = ws[TAB_VO2 + j*256 + tid];
  const float cc = ws[TAB_C2 + tid];
  __syncthreads();
  for(int r=0;r<32;++r){
    float a = cc;
    #pragma unroll
    for(int j=0;j<24;++j) a = fmaf(sY[r*24+j], vj[j], a);
    a = a>0.f ? a : 0.f;
    g1[(size_t)(rowb+r)*HH + tid] = a;
  }
}

// ---------- generic GEMM: C = op(A @ W^T + bias), K=256 fixed ----------
#define MAD_ROW(i, AV) \
  acc[i][0]=fmaf(AV.x,b0.x,acc[i][0]); acc[i][1]=fmaf(AV.x,b0.y,acc[i][1]); acc[i][2]=fmaf(AV.x,b0.z,acc[i][2]); acc[i][3]=fmaf(AV.x,b0.w,acc[i][3]); \
  acc[i][0]=fmaf(AV.y,b1.x,acc[i][0]); acc[i][1]=fmaf(AV.y,b1.y,acc[i][1]); acc[i][2]=fmaf(AV.y,b1.z,acc[i][2]); acc[i][3]=fmaf(AV.y,b1.w,acc[i][3]); \
  acc[i][0]=fmaf(AV.z,b2.x,acc[i][0]); acc[i][1]=fmaf(AV.z,b2.y,acc[i][1]); acc[i][2]=fmaf(AV.z,b2.z,acc[i][2]); acc[i][3]=fmaf(AV.z,b2.w,acc[i][3]); \
  acc[i][0]=fmaf(AV.w,b3.x,acc[i][0]); acc[i][1]=fmaf(AV.w,b3.y,acc[i][1]); acc[i][2]=fmaf(AV.w,b3.z,acc[i][2]); acc[i][3]=fmaf(AV.w,b3.w,acc[i][3]);

template<bool RELU, bool BIAS, bool SCATTER>
__global__ __launch_bounds__(256) void k_gemm(const float* __restrict__ A,
                                              const float* __restrict__ W,
                                              const float* __restrict__ bias,
                                              float* __restrict__ C,
                                              int Ncols){
  __shared__ __align__(16) float As[64][20];
  __shared__ __align__(16) float Bs[16][68];
  const int rowb = blockIdx.y * 64;
  const int colb = blockIdx.x * 64;
  const int tid = threadIdx.x;
  const int tx = tid & 15;
  const int ty = tid >> 4;
  const int sr = tid >> 2;
  const int sc = (tid & 3) * 4;
  float acc[4][4] = {};
  for(int kt = 0; kt < 16; ++kt){
    const float4 av = *(const float4*)&A[(size_t)(rowb+sr)*HH + kt*16 + sc];
    float4 wv = make_float4(0.f,0.f,0.f,0.f);
    if(colb + sr < Ncols) wv = *(const float4*)&W[(size_t)(colb+sr)*HH + kt*16 + sc];
    __syncthreads();
    *(float4*)&As[sr][sc] = av;
    Bs[sc+0][sr] = wv.x; Bs[sc+1][sr] = wv.y; Bs[sc+2][sr] = wv.z; Bs[sc+3][sr] = wv.w;
    __syncthreads();
    #pragma unroll
    for(int kc = 0; kc < 4; ++kc){
      const float4 a0 = *(const float4*)&As[ty*4+0][kc*4];
      const float4 a1 = *(const float4*)&As[ty*4+1][kc*4];
      const float4 a2 = *(const float4*)&As[ty*4+2][kc*4];
      const float4 a3 = *(const float4*)&As[ty*4+3][kc*4];
      const float4 b0 = *(const float4*)&Bs[kc*4+0][tx*4];
      const float4 b1 = *(const float4*)&Bs[kc*4+1][tx*4];
      const float4 b2 = *(const float4*)&Bs[kc*4+2][tx*4];
      const float4 b3 = *(const float4*)&Bs[kc*4+3][tx*4];
      MAD_ROW(0, a0) MAD_ROW(1, a1) MAD_ROW(2, a2) MAD_ROW(3, a3)
    }
  }
  #pragma unroll
  for(int i = 0; i < 4; ++i){
    const int row = rowb + ty*4 + i;
    if(!SCATTER){
      float4 v;
      v.x = acc[i][0]; v.y = acc[i][1]; v.z = acc[i][2]; v.w = acc[i][3];
      const int col = colb + tx*4;
      if(BIAS){ v.x += bias[col]; v.y += bias[col+1]; v.z += bias[col+2]; v.w += bias[col+3]; }
      if(RELU){ v.x = v.x>0.f?v.x:0.f; v.y = v.y>0.f?v.y:0.f; v.z = v.z>0.f?v.z:0.f; v.w = v.w>0.f?v.w:0.f; }
      *(float4*)&C[(size_t)row*HH + col] = v;
    } else {
      #pragma unroll
      for(int j = 0; j < 4; ++j){
        const int col = colb + tx*4 + j;
        if(col < Ncols){
          float v = acc[i][j];
          if(BIAS) v += bias[col];
          if(RELU) v = v>0.f?v:0.f;
          const int b = row >> 10, n = row & 1023;
          const int p = col / 3, f = col - p*3;
          C[(size_t)(((b*PP + p)*NN + n)*FF + f)] = v;
        }
      }
    }
  }
}

extern "C" void kernel_launch(void* const* d_in, const int* in_sizes, int n_in,
                              void* d_out, int out_size, void* d_ws, size_t ws_size,
                              hipStream_t stream){
  (void)in_sizes; (void)n_in; (void)out_size; (void)ws_size;
  const float* x     = (const float*)d_in[0];
  const float* w_in  = (const float*)d_in[2];
  const float* b_in  = (const float*)d_in[3];
  const float* w_s1  = (const float*)d_in[4];
  const float* b_s1  = (const float*)d_in[5];
  const float* w_s2  = (const float*)d_in[6];
  const float* w_qkv = (const float*)d_in[8];
  const float* b_qkv = (const float*)d_in[9];
  const float* w_o   = (const float*)d_in[10];
  const float* b_o   = (const float*)d_in[11];
  const float* w_g1  = (const float*)d_in[12];
  const float* b_g1  = (const float*)d_in[13];
  const float* w_g2  = (const float*)d_in[14];
  const float* b_g2  = (const float*)d_in[15];
  const float* w_out = (const float*)d_in[16];
  const float* b_out = (const float*)d_in[17];
  float* ws = (float*)d_ws;

  float* phi = ws + PHIOFF;
  float* y   = ws + YSPOFF;
  float* Yt  = ws + YTOFF;
  float* g1  = ws + G1OFF;
  float* g2  = ws + G2OFF;
  float* outp = (float*)d_out;

  k_preS  <<<8,   256, 0, stream>>>(w_s1, w_s2, w_in, b_in, ws);
  k_preQKV<<<12,  256, 0, stream>>>(w_qkv, b_qkv, w_in, b_in, ws);
  k_tab   <<<1,   256, 0, stream>>>(b_s1, ws);
  k_vo1   <<<4,   256, 0, stream>>>(w_o, b_o, ws);
  k_vo2   <<<100, 256, 0, stream>>>(w_g1, b_g1, ws);
  k_phi   <<<RTOT/256, 256, 0, stream>>>(x, ws, (float4*)phi);
  k_spatial<<<BB*TT*4, 256, 0, stream>>>(x, (const float4*)phi, y);
  k_temporal<<<BB*NN*8/256, 256, 0, stream>>>(y, ws, Yt);
  k_g1    <<<BB*NN/32, 256, 0, stream>>>(ws, g1);
  k_gemm<true, true,false><<<dim3(4, BB*NN/64), 256, 0, stream>>>(g1, w_g2, b_g2, g2, HH);
  k_gemm<false,true,true ><<<dim3(1, BB*NN/64), 256, 0, stream>>>(g2, w_out, b_out, outp, PP*FF);
}